// Round 17
// baseline (15.795 us; speedup 1.0000x reference)
//
#include <hip/hip_runtime.h>
#include <math.h>

#define LOG2E 1.4426950408889634f
#define LN2   0.6931471805599453f
#define NW 16   // waves per block
#define CH 64   // train points per chunk per wave (= 2 tiles of 32)

typedef short short8 __attribute__((ext_vector_type(8)));
typedef float f32x16 __attribute__((ext_vector_type(16)));

__device__ inline unsigned int cvtpk_bf16(float lo, float hi) {
    unsigned int r;
    asm("v_cvt_pk_bf16_f32 %0, %1, %2" : "=v"(r) : "v"(lo), "v"(hi));
    return r;   // low16 = bf16(lo), high16 = bf16(hi)
}

// R16 structure (256 blocks x 16 waves; block = 16 test rows; 32x32x16 MFMA
// with M half-padded; exp-weight identity; wave-private LDS staging) with a
// DEEPENED PIPELINE: double-buffered LDS chunks + two raw register sets so
// global loads are issued ~2 chunks (1 full iteration, 300+ cyc) before
// their LDS write, covering L2 latency; LDS writes always target the buffer
// not being read. No barriers in the loop (wave-private LDS, in-order DS).
__global__ __launch_bounds__(1024, 4) void kde_fused(
    const float* __restrict__ testX, const float* __restrict__ trainX,
    float* __restrict__ out, int nTest, int nTrain, int nch, float Z)
{
    const int tid  = threadIdx.x;
    const int lane = tid & 63;
    const int w    = tid >> 6;            // wave 0..15
    const int c    = lane & 31;           // MFMA col (train pt) / A-row index
    const int half = lane >> 5;           // k-half (dims 0-7 / 8-15)
    const int rowBase = blockIdx.x * 16;

    __shared__ short8 stage[NW][2][2 * CH];         // 64 KB (2 chunk buffers)
    __shared__ float  wbuf[NW][2][CH];              // 8 KB
    __shared__ float  xnbuf[16];
    __shared__ __align__(16) float red2[NW][32][20];// 40 KB
    __shared__ __align__(16) float red3[16][68];    // 4.3 KB

    // ---- A fragment: rows rowBase+(c&15) (dup'd for c>=16), bf16(x*log2e) ----
    const int mrow = min(rowBase + (c & 15), nTest - 1);
    const float4* xp = (const float4*)(testX + (size_t)mrow * 16) + half * 2;
    float4 xa = xp[0], xb = xp[1];
    float f0 = xa.x*LOG2E, f1 = xa.y*LOG2E, f2 = xa.z*LOG2E, f3 = xa.w*LOG2E;
    float f4 = xb.x*LOG2E, f5 = xb.y*LOG2E, f6 = xb.z*LOG2E, f7 = xb.w*LOG2E;
    float pn = ((f0*f0 + f1*f1) + (f2*f2 + f3*f3))
             + ((f4*f4 + f5*f5) + (f6*f6 + f7*f7));
    float xn2 = (pn + __shfl_xor(pn, 32)) * (0.5f / LOG2E);  // 0.5*log2e*||x||^2
    union { unsigned int u[4]; short8 s; } au;
    au.u[0] = cvtpk_bf16(f0, f1);
    au.u[1] = cvtpk_bf16(f2, f3);
    au.u[2] = cvtpk_bf16(f4, f5);
    au.u[3] = cvtpk_bf16(f6, f7);
    const short8 afrag = au.s;
    if (w == 0 && half == 0 && c < 16) xnbuf[c] = xn2;

    // ---- wave's train slice ----
    const int nMax = nTrain - 1;
    const int tb   = w * nch * CH;
    const int rdU  = (c * 2 + half) ^ ((c >> 2) & 7);   // swizzled read unit
    const int pp   = lane & 31, ti64 = lane >> 5;
    const int u0s  = (pp * 2 + 0) ^ ((pp >> 2) & 7);
    const int u1s  = (pp * 2 + 1) ^ ((pp >> 2) & 7);

    float rs[8];
    #pragma unroll
    for (int i = 0; i < 8; ++i) rs[i] = 0.0f;
    const f32x16 zc = {0.f,0.f,0.f,0.f,0.f,0.f,0.f,0.f,
                       0.f,0.f,0.f,0.f,0.f,0.f,0.f,0.f};

    // pure loads (no dependent use -> no vmcnt stall at issue)
    #define LOADPT(CHN, Q0,Q1,Q2,Q3,VLD) {                                    \
        int gi = tb + (CHN) * CH + lane;                                      \
        VLD = (gi <= nMax);                                                   \
        const float4* p = (const float4*)(trainX + (size_t)min(gi, nMax)*16); \
        Q0 = p[0]; Q1 = p[1]; Q2 = p[2]; Q3 = p[3]; }

    // norm + exp-weight + bf16 pack + LDS write (consumes the raw set)
    #define WRITEPT(Q0,Q1,Q2,Q3,VLD,B) {                                      \
        float nrm = ((Q0.x*Q0.x + Q0.y*Q0.y) + (Q0.z*Q0.z + Q0.w*Q0.w))       \
                  + ((Q1.x*Q1.x + Q1.y*Q1.y) + (Q1.z*Q1.z + Q1.w*Q1.w))       \
                  + ((Q2.x*Q2.x + Q2.y*Q2.y) + (Q2.z*Q2.z + Q2.w*Q2.w))       \
                  + ((Q3.x*Q3.x + Q3.y*Q3.y) + (Q3.z*Q3.z + Q3.w*Q3.w));      \
        float wvv = (VLD) ? __builtin_amdgcn_exp2f(-0.5f*LOG2E*nrm) : 0.0f;   \
        union { unsigned int u[4]; short8 s; } bu0, bu1;                      \
        bu0.u[0]=cvtpk_bf16(Q0.x,Q0.y); bu0.u[1]=cvtpk_bf16(Q0.z,Q0.w);       \
        bu0.u[2]=cvtpk_bf16(Q1.x,Q1.y); bu0.u[3]=cvtpk_bf16(Q1.z,Q1.w);       \
        bu1.u[0]=cvtpk_bf16(Q2.x,Q2.y); bu1.u[1]=cvtpk_bf16(Q2.z,Q2.w);       \
        bu1.u[2]=cvtpk_bf16(Q3.x,Q3.y); bu1.u[3]=cvtpk_bf16(Q3.z,Q3.w);       \
        stage[w][B][ti64 * 64 + u0s] = bu0.s;                                 \
        stage[w][B][ti64 * 64 + u1s] = bu1.s;                                 \
        wbuf[w][B][lane] = wvv; }

    // consume one staged chunk (2 tiles of 32): both reads+MFMAs issued
    // before the exp2/fma chains (MFMA1 hides under tile0's consumption)
    #define INNER(B) {                                                        \
        short8 bf0 = stage[w][B][rdU];                                        \
        short8 bf1 = stage[w][B][64 + rdU];                                   \
        float  wt0 = wbuf[w][B][c];                                           \
        float  wt1 = wbuf[w][B][32 + c];                                      \
        f32x16 d0 = __builtin_amdgcn_mfma_f32_32x32x16_bf16(afrag,bf0,zc,0,0,0);\
        f32x16 d1 = __builtin_amdgcn_mfma_f32_32x32x16_bf16(afrag,bf1,zc,0,0,0);\
        _Pragma("unroll")                                                     \
        for (int r = 0; r < 8; ++r)                                           \
            rs[r] += __builtin_amdgcn_exp2f(d0[r]) * wt0;                     \
        _Pragma("unroll")                                                     \
        for (int r = 0; r < 8; ++r)                                           \
            rs[r] += __builtin_amdgcn_exp2f(d1[r]) * wt1; }

    // ---- pipeline: L 2-ahead, dbuf LDS; nch even, >= 2 ----
    float4 ra0,ra1,ra2,ra3, rb0,rb1,rb2,rb3;
    bool vA, vB;
    LOADPT(0, ra0,ra1,ra2,ra3, vA);
    LOADPT(1, rb0,rb1,rb2,rb3, vB);
    WRITEPT(ra0,ra1,ra2,ra3, vA, 0);
    int ch = 0;
    for (; ch + 2 < nch; ch += 2) {
        INNER(0);                                    // chunk ch
        LOADPT(ch + 2, ra0,ra1,ra2,ra3, vA);
        WRITEPT(rb0,rb1,rb2,rb3, vB, 1);             // chunk ch+1 -> buf1
        INNER(1);                                    // chunk ch+1
        LOADPT(ch + 3, rb0,rb1,rb2,rb3, vB);
        WRITEPT(ra0,ra1,ra2,ra3, vA, 0);             // chunk ch+2 -> buf0
    }
    INNER(0);                                        // chunk nch-2
    WRITEPT(rb0,rb1,rb2,rb3, vB, 1);
    INNER(1);                                        // chunk nch-1

    #undef LOADPT
    #undef WRITEPT
    #undef INNER

    // ---- reduce: rs[reg] = col c, row (reg&3)+8*(reg>>2)+4*half (0-15) ----
    {
        float4 v0 = make_float4(rs[0], rs[1], rs[2], rs[3]);
        float4 v1 = make_float4(rs[4], rs[5], rs[6], rs[7]);
        *(float4*)&red2[w][c][half * 4]     = v0;   // rows 0-3 + 4*half
        *(float4*)&red2[w][c][8 + half * 4] = v1;   // rows 8-11 + 4*half
    }
    __syncthreads();

    // pass 1: 1024 threads: row = t&15, seg = t>>4 (16 waves x 4 col-groups)
    {
        int row = tid & 15, seg = tid >> 4;
        int wv2 = seg >> 2, cb = (seg & 3) * 8;
        float s = 0.0f;
        #pragma unroll
        for (int i = 0; i < 8; ++i) s += red2[wv2][cb + i][row];
        red3[row][seg] = s;
    }
    __syncthreads();

    // pass 2: 16 threads finalize rows (16 x float4 per thread)
    if (tid < 16) {
        int row = rowBase + tid;
        if (row < nTest) {
            float s = 0.0f;
            #pragma unroll
            for (int k = 0; k < 16; ++k) {
                float4 v = *(const float4*)&red3[tid][k * 4];
                s += (v.x + v.y) + (v.z + v.w);
            }
            out[row] = __logf(s) - xnbuf[tid] * LN2 - Z;
        }
    }
}

extern "C" void kernel_launch(void* const* d_in, const int* in_sizes, int n_in,
                              void* d_out, int out_size, void* d_ws, size_t ws_size,
                              hipStream_t stream) {
    const float* testX  = (const float*)d_in[0];
    const float* trainX = (const float*)d_in[1];
    float* out = (float*)d_out;

    const int D = 16;
    const int nTest  = in_sizes[0] / D;   // 4096
    const int nTrain = in_sizes[1] / D;   // 8192

    const float Z = 0.5f * (float)D * logf(2.0f * (float)M_PI) + logf((float)nTrain);

    int nch = (nTrain + NW * CH - 1) / (NW * CH);   // chunks per wave (8)
    nch = (nch + 1) & ~1;                           // even (pipeline needs pairs)
    const int grid = (nTest + 15) / 16;             // 256 blocks, 16 rows

    kde_fused<<<grid, 1024, 0, stream>>>(testX, trainX, out, nTest, nTrain, nch, Z);
}

// Round 18
// 15.564 us; speedup vs baseline: 1.0149x; 1.0149x over previous
//
#include <hip/hip_runtime.h>
#include <math.h>

#define LOG2E 1.4426950408889634f
#define LN2   0.6931471805599453f
#define NW 16   // waves per block

typedef short short8 __attribute__((ext_vector_type(8)));
typedef float f32x16 __attribute__((ext_vector_type(16)));

__device__ inline unsigned int cvtpk_bf16(float lo, float hi) {
    unsigned int r;
    asm("v_cvt_pk_bf16_f32 %0, %1, %2" : "=v"(r) : "v"(lo), "v"(hi));
    return r;   // low16 = bf16(lo), high16 = bf16(hi)
}

// ONE dispatch, ZERO staging (direct-to-register B-fragments).
// 256 blocks x 1024 threads (16 waves, 1 blk/CU). Block = 16 test rows
// (32x32x16 MFMA, M half-padded: rows 16-31 dup rows 0-15, only output
// regs 0-7 consumed). Waves partition train into 16-tile slices (32 pts).
// KEY: in the 32x32x16 B layout, lane (c, half) needs dims half*8..+7 of
// train point tile*32+c = ONE contiguous 32B load, unique per lane across
// the whole wave -> perfectly coalesced, no LDS, no cross-lane sharing
// except one shfl_xor(32) to combine the two half-norms.
// Weight identity: sum exp2(dot - xn - yn) = exp2(-xn) * sum exp2(dot) * w,
// w = exp2(-0.5*log2e*||y||^2) in f32; -xn*ln2 folds into the final log.
__global__ __launch_bounds__(1024, 4) void kde_fused(
    const float* __restrict__ testX, const float* __restrict__ trainX,
    float* __restrict__ out, int nTest, int nTrain, int nt, float Z)
{
    const int tid  = threadIdx.x;
    const int lane = tid & 63;
    const int w    = tid >> 6;            // wave 0..15
    const int c    = lane & 31;           // MFMA col (train pt) / A-row index
    const int half = lane >> 5;           // k-half (dims 0-7 / 8-15)
    const int rowBase = blockIdx.x * 16;

    __shared__ float xnbuf[16];
    __shared__ __align__(16) float red2[NW][32][20];  // 40 KB
    __shared__ __align__(16) float red3[16][68];      // 4.3 KB

    // ---- A fragment: rows rowBase+(c&15) (dup'd for c>=16), bf16(x*log2e) ----
    const int mrow = min(rowBase + (c & 15), nTest - 1);
    const float4* xp = (const float4*)(testX + (size_t)mrow * 16) + half * 2;
    float4 xa = xp[0], xb = xp[1];
    float f0 = xa.x*LOG2E, f1 = xa.y*LOG2E, f2 = xa.z*LOG2E, f3 = xa.w*LOG2E;
    float f4 = xb.x*LOG2E, f5 = xb.y*LOG2E, f6 = xb.z*LOG2E, f7 = xb.w*LOG2E;
    float pnx = ((f0*f0 + f1*f1) + (f2*f2 + f3*f3))
              + ((f4*f4 + f5*f5) + (f6*f6 + f7*f7));
    float xn2 = (pnx + __shfl_xor(pnx, 32)) * (0.5f / LOG2E); // 0.5*log2e*||x||^2
    union { unsigned int u[4]; short8 s; } au;
    au.u[0] = cvtpk_bf16(f0, f1);
    au.u[1] = cvtpk_bf16(f2, f3);
    au.u[2] = cvtpk_bf16(f4, f5);
    au.u[3] = cvtpk_bf16(f6, f7);
    const short8 afrag = au.s;
    if (w == 0 && half == 0 && c < 16) xnbuf[c] = xn2;

    // ---- wave's train slice: nt tiles of 32 pts ----
    const int nMax = nTrain - 1;
    const int tb   = w * nt * 32;
    const float* tbase = trainX + (size_t)half * 8;   // this lane's dim-half

    float rs[8];
    #pragma unroll
    for (int i = 0; i < 8; ++i) rs[i] = 0.0f;
    const f32x16 zc = {0.f,0.f,0.f,0.f,0.f,0.f,0.f,0.f,
                       0.f,0.f,0.f,0.f,0.f,0.f,0.f,0.f};

    // pure load of tile T: this lane's 32B half of point tb+T*32+c
    #define LOADT(T, QA, QB) {                                                \
        int gi = tb + (T) * 32 + c;                                           \
        const float4* p = (const float4*)(tbase + (size_t)min(gi, nMax)*16);  \
        QA = p[0]; QB = p[1]; }

    // consume tile T: half-norm + shfl combine -> f32 weight; cvt_pk -> B;
    // MFMA; 8x exp2+fma into rs.
    #define PROC(T, QA, QB) {                                                 \
        float pn = ((QA.x*QA.x + QA.y*QA.y) + (QA.z*QA.z + QA.w*QA.w))        \
                 + ((QB.x*QB.x + QB.y*QB.y) + (QB.z*QB.z + QB.w*QB.w));       \
        float fn = pn + __shfl_xor(pn, 32);                                   \
        float wt = (tb + (T) * 32 + c <= nMax)                                \
                 ? __builtin_amdgcn_exp2f(-0.5f * LOG2E * fn) : 0.0f;         \
        union { unsigned int u[4]; short8 s; } bu;                            \
        bu.u[0] = cvtpk_bf16(QA.x, QA.y);                                     \
        bu.u[1] = cvtpk_bf16(QA.z, QA.w);                                     \
        bu.u[2] = cvtpk_bf16(QB.x, QB.y);                                     \
        bu.u[3] = cvtpk_bf16(QB.z, QB.w);                                     \
        f32x16 d = __builtin_amdgcn_mfma_f32_32x32x16_bf16(afrag,bu.s,zc,0,0,0);\
        _Pragma("unroll")                                                     \
        for (int r = 0; r < 8; ++r)                                           \
            rs[r] += __builtin_amdgcn_exp2f(d[r]) * wt; }

    // ---- 2-deep register pipeline over nt tiles (nt even) ----
    float4 a0,b0,a1,b1;
    LOADT(0, a0, b0);
    for (int t = 0; t < nt; t += 2) {
        LOADT(t + 1, a1, b1);
        PROC(t, a0, b0);
        if (t + 2 < nt) LOADT(t + 2, a0, b0);
        PROC(t + 1, a1, b1);
    }
    #undef LOADT
    #undef PROC

    // ---- reduce: rs[reg] = col c, row (reg&3)+8*(reg>>2)+4*half (0-15) ----
    {
        float4 v0 = make_float4(rs[0], rs[1], rs[2], rs[3]);
        float4 v1 = make_float4(rs[4], rs[5], rs[6], rs[7]);
        *(float4*)&red2[w][c][half * 4]     = v0;   // rows 0-3 + 4*half
        *(float4*)&red2[w][c][8 + half * 4] = v1;   // rows 8-11 + 4*half
    }
    __syncthreads();

    // pass 1: 1024 threads: row = t&15, seg = t>>4 (16 waves x 4 col-groups)
    {
        int row = tid & 15, seg = tid >> 4;
        int wv2 = seg >> 2, cb = (seg & 3) * 8;
        float s = 0.0f;
        #pragma unroll
        for (int i = 0; i < 8; ++i) s += red2[wv2][cb + i][row];
        red3[row][seg] = s;
    }
    __syncthreads();

    // pass 2: 16 threads finalize rows
    if (tid < 16) {
        int row = rowBase + tid;
        if (row < nTest) {
            float s = 0.0f;
            #pragma unroll
            for (int k = 0; k < 16; ++k) {
                float4 v = *(const float4*)&red3[tid][k * 4];
                s += (v.x + v.y) + (v.z + v.w);
            }
            out[row] = __logf(s) - xnbuf[tid] * LN2 - Z;
        }
    }
}

extern "C" void kernel_launch(void* const* d_in, const int* in_sizes, int n_in,
                              void* d_out, int out_size, void* d_ws, size_t ws_size,
                              hipStream_t stream) {
    const float* testX  = (const float*)d_in[0];
    const float* trainX = (const float*)d_in[1];
    float* out = (float*)d_out;

    const int D = 16;
    const int nTest  = in_sizes[0] / D;   // 4096
    const int nTrain = in_sizes[1] / D;   // 8192

    const float Z = 0.5f * (float)D * logf(2.0f * (float)M_PI) + logf((float)nTrain);

    // tiles of 32 per wave, even for the 2-deep pipeline
    int nt = (nTrain + NW * 32 - 1) / (NW * 32);    // 16 at bench size
    nt = (nt + 1) & ~1;
    const int grid = (nTest + 15) / 16;             // 256 blocks, 16 rows

    kde_fused<<<grid, 1024, 0, stream>>>(testX, trainX, out, nTest, nTrain, nt, Z);
}

// Round 19
// 14.840 us; speedup vs baseline: 1.0644x; 1.0488x over previous
//
#include <hip/hip_runtime.h>
#include <math.h>

#define LOG2E 1.4426950408889634f
#define LN2   0.6931471805599453f
#define NW 16   // waves per block
#define CH 64   // train points staged per chunk per wave (= 2 tiles of 32)

typedef short short8 __attribute__((ext_vector_type(8)));
typedef float f32x16 __attribute__((ext_vector_type(16)));

__device__ inline unsigned int cvtpk_bf16(float lo, float hi) {
    unsigned int r;
    asm("v_cvt_pk_bf16_f32 %0, %1, %2" : "=v"(r) : "v"(lo), "v"(hi));
    return r;   // low16 = bf16(lo), high16 = bf16(hi)
}

// BEST-KNOWN (R16, 15.06us): ONE dispatch. grid = nTest/16 blocks (256 ->
// ALL CUs busy) x 1024 threads (16 waves). Block owns 16 test rows;
// A-operand M=32 half-padded (rows 16-31 dup rows 0-15); only output regs
// 0-7 consumed -> M-waste hits only the non-bottleneck MFMA pipe.
// Waves partition train (512 pts = 8 chunks of 64 = 2 tiles of 32), staging
// into PRIVATE 2KB LDS: 32B/pt bf16 (2 variants: dims0-7, dims8-15),
// XOR-swizzled, + f32 weight w = exp2(-0.5*log2e*||y||^2) (padded pts w=0).
// Inner per chunk: 2x{ds_read_b128 + ds_read_b32} -> 2 MFMAs back-to-back
// -> tile0's 8 exp2+fma (hides tile1's MFMA) -> tile1.
// Identity: sum exp2(dot - xn - yn) = exp2(-xn) * sum exp2(dot) * w;
// -xn*ln2 folds into the final log. No barriers in the staging/inner loop
// (wave-private LDS, in-order per-wave DS ops).
__global__ __launch_bounds__(1024, 4) void kde_fused(
    const float* __restrict__ testX, const float* __restrict__ trainX,
    float* __restrict__ out, int nTest, int nTrain, int nch, float Z)
{
    const int tid  = threadIdx.x;
    const int lane = tid & 63;
    const int w    = tid >> 6;            // wave 0..15
    const int c    = lane & 31;           // MFMA col (train pt) / A-row index
    const int half = lane >> 5;           // k-half (dims 0-7 / 8-15)
    const int rowBase = blockIdx.x * 16;

    __shared__ short8 stage[NW][2 * CH];            // 32 KB
    __shared__ float  wbuf[NW][CH];                 // 4 KB
    __shared__ float  xnbuf[16];
    __shared__ __align__(16) float red2[NW][32][20];// 40 KB
    __shared__ float  red3[16][68];                 // 4.3 KB

    // ---- A fragment: rows rowBase+(c&15) (dup'd for c>=16), bf16(x*log2e) ----
    const int mrow = min(rowBase + (c & 15), nTest - 1);
    const float4* xp = (const float4*)(testX + (size_t)mrow * 16) + half * 2;
    float4 xa = xp[0], xb = xp[1];
    float f0 = xa.x*LOG2E, f1 = xa.y*LOG2E, f2 = xa.z*LOG2E, f3 = xa.w*LOG2E;
    float f4 = xb.x*LOG2E, f5 = xb.y*LOG2E, f6 = xb.z*LOG2E, f7 = xb.w*LOG2E;
    float pn = ((f0*f0 + f1*f1) + (f2*f2 + f3*f3))
             + ((f4*f4 + f5*f5) + (f6*f6 + f7*f7));
    float xn2 = (pn + __shfl_xor(pn, 32)) * (0.5f / LOG2E);  // 0.5*log2e*||x||^2
    union { unsigned int u[4]; short8 s; } au;
    au.u[0] = cvtpk_bf16(f0, f1);
    au.u[1] = cvtpk_bf16(f2, f3);
    au.u[2] = cvtpk_bf16(f4, f5);
    au.u[3] = cvtpk_bf16(f6, f7);
    const short8 afrag = au.s;
    if (w == 0 && half == 0 && c < 16) xnbuf[c] = xn2;

    // ---- wave's train slice ----
    const int nMax = nTrain - 1;
    const int tb   = w * nch * CH;
    const int rdU  = (c * 2 + half) ^ ((c >> 2) & 7);   // swizzled read unit

    float4 q0, q1, q2, q3; float wv;
    auto LOADRAW = [&](int ch) {          // lane loads pt ch*64+lane (64B)
        int gi = tb + ch * CH + lane;
        const float4* p = (const float4*)(trainX + (size_t)min(gi, nMax) * 16);
        q0 = p[0]; q1 = p[1]; q2 = p[2]; q3 = p[3];
        float nrm = ((q0.x*q0.x + q0.y*q0.y) + (q0.z*q0.z + q0.w*q0.w))
                  + ((q1.x*q1.x + q1.y*q1.y) + (q1.z*q1.z + q1.w*q1.w))
                  + ((q2.x*q2.x + q2.y*q2.y) + (q2.z*q2.z + q2.w*q2.w))
                  + ((q3.x*q3.x + q3.y*q3.y) + (q3.z*q3.z + q3.w*q3.w));
        wv = (gi <= nMax) ? __builtin_amdgcn_exp2f(-0.5f * LOG2E * nrm) : 0.0f;
    };
    auto WRITEPT = [&]() {
        const int pp = lane & 31, ti = lane >> 5;
        const int u0 = (pp * 2 + 0) ^ ((pp >> 2) & 7);
        const int u1 = (pp * 2 + 1) ^ ((pp >> 2) & 7);
        union { unsigned int u[4]; short8 s; } b0, b1;
        b0.u[0] = cvtpk_bf16(q0.x, q0.y); b0.u[1] = cvtpk_bf16(q0.z, q0.w);
        b0.u[2] = cvtpk_bf16(q1.x, q1.y); b0.u[3] = cvtpk_bf16(q1.z, q1.w);
        b1.u[0] = cvtpk_bf16(q2.x, q2.y); b1.u[1] = cvtpk_bf16(q2.z, q2.w);
        b1.u[2] = cvtpk_bf16(q3.x, q3.y); b1.u[3] = cvtpk_bf16(q3.z, q3.w);
        stage[w][ti * 64 + u0] = b0.s;    // variant 0: dims 0-7
        stage[w][ti * 64 + u1] = b1.s;    // variant 1: dims 8-15
        wbuf[w][lane] = wv;
    };

    float rs[8];
    #pragma unroll
    for (int i = 0; i < 8; ++i) rs[i] = 0.0f;

    const f32x16 zc = {0.f,0.f,0.f,0.f,0.f,0.f,0.f,0.f,
                       0.f,0.f,0.f,0.f,0.f,0.f,0.f,0.f};
    auto INNER = [&]() {
        short8 bf0 = stage[w][rdU];
        short8 bf1 = stage[w][64 + rdU];
        float  wt0 = wbuf[w][c];
        float  wt1 = wbuf[w][32 + c];
        f32x16 d0 = __builtin_amdgcn_mfma_f32_32x32x16_bf16(afrag, bf0, zc, 0,0,0);
        f32x16 d1 = __builtin_amdgcn_mfma_f32_32x32x16_bf16(afrag, bf1, zc, 0,0,0);
        #pragma unroll
        for (int r = 0; r < 8; ++r)
            rs[r] += __builtin_amdgcn_exp2f(d0[r]) * wt0;
        #pragma unroll
        for (int r = 0; r < 8; ++r)
            rs[r] += __builtin_amdgcn_exp2f(d1[r]) * wt1;
    };

    // Pipeline: load(ch+1) || inner(ch) || write(ch+1); wave-private LDS.
    LOADRAW(0);
    WRITEPT();
    for (int ch = 0; ch < nch - 1; ++ch) {
        LOADRAW(ch + 1);
        INNER();
        WRITEPT();
    }
    INNER();

    // ---- reduce: rs[reg] = col c, row (reg&3)+8*(reg>>2)+4*half (0-15) ----
    {
        float4 v0 = make_float4(rs[0], rs[1], rs[2], rs[3]);
        float4 v1 = make_float4(rs[4], rs[5], rs[6], rs[7]);
        *(float4*)&red2[w][c][half * 4]     = v0;   // rows 0-3 + 4*half
        *(float4*)&red2[w][c][8 + half * 4] = v1;   // rows 8-11 + 4*half
    }
    __syncthreads();

    // pass 1: 1024 threads: row = t&15, seg = t>>4 (16 waves x 4 col-groups)
    {
        int row = tid & 15, seg = tid >> 4;
        int wv2 = seg >> 2, cb = (seg & 3) * 8;
        float s = 0.0f;
        #pragma unroll
        for (int i = 0; i < 8; ++i) s += red2[wv2][cb + i][row];
        red3[row][seg] = s;
    }
    __syncthreads();

    // pass 2: 16 threads finalize rows
    if (tid < 16) {
        int row = rowBase + tid;
        if (row < nTest) {
            float s = 0.0f;
            #pragma unroll
            for (int k = 0; k < 64; ++k) s += red3[tid][k];
            out[row] = __logf(s) - xnbuf[tid] * LN2 - Z;
        }
    }
}

extern "C" void kernel_launch(void* const* d_in, const int* in_sizes, int n_in,
                              void* d_out, int out_size, void* d_ws, size_t ws_size,
                              hipStream_t stream) {
    const float* testX  = (const float*)d_in[0];
    const float* trainX = (const float*)d_in[1];
    float* out = (float*)d_out;

    const int D = 16;
    const int nTest  = in_sizes[0] / D;   // 4096
    const int nTrain = in_sizes[1] / D;   // 8192

    const float Z = 0.5f * (float)D * logf(2.0f * (float)M_PI) + logf((float)nTrain);

    const int nch  = (nTrain + NW * CH - 1) / (NW * CH);  // chunks per wave (8)
    const int grid = (nTest + 15) / 16;                   // 256 blocks, 16 rows

    kde_fused<<<grid, 1024, 0, stream>>>(testX, trainX, out, nTest, nTrain, nch, Z);
}